// Round 12
// baseline (381.010 us; speedup 1.0000x reference)
//
#include <hip/hip_runtime.h>
#include <hip/hip_fp16.h>
#include <math.h>

// ---------------------------------------------------------------------------
// GIN link scorer. Pipeline:
//   bin:  XCD-sharded, sub-chunk-reserved binning of edges into 1563 buckets
//         of 64 dst nodes (payload (dstlow<<17)|src).
//   sort: ONE dst-sort pass per bucket (hist -> wave scan -> placement),
//         results to global seds (sorted src per node run) + rsg (run
//         offsets). R11: agg1+agg2 each rebuilt this sort (~80us of agg2's
//         100us); now it's paid once.
//   agg1: stage seds run -> wave-per-node gather x[src] -> xsum.
//   mlpA: weights direct from global (wave-uniform -> s_load scalar path,
//         R10), launch_bounds(256,2) so t[64] stays in VGPRs (R7).
//         h1 = relu(relu(xsum@w1a+b1a)@w2a+b2a); g1h = fp16(h1@w1b) [N,32].
//   agg2: stage seds run -> wave-per-node gather g1h rows via __half2
//         (4 lanes/row, 8 rows in flight/lane); u = relu(hsum+self+b1b);
//         z1=u.v1+c1, z2=u.v2+c2 (MLP-B collapsed to two 32-vectors).
//   score: out[c] = sigmoid(z1[a]+z2[b]+bs).
// ---------------------------------------------------------------------------

#define NPB 64        // nodes per bucket
#define NBKA 1600     // allocated buckets (1563 used)
#define NSHARD 8
#define SCAP 640      // per shard-bucket capacity; mean 500, sigma 22 -> +6σ
#define BCAP 4608     // per-bucket capacity; mean 4096, sigma 64 -> +8σ
#define BIN_BLOCKS 256
#define SUBCHUNK 8192

__global__ __launch_bounds__(1024) void bin_kernel(
    const int* __restrict__ src, const int* __restrict__ dst,
    int* __restrict__ cursor, int* __restrict__ bdata, long E) {
    __shared__ int h[NBKA];    // per-sub-chunk counts, then local cursor
    __shared__ int gb[NBKA];   // reserved global base per bucket
    int tid = threadIdx.x;
    int sh = blockIdx.x & (NSHARD - 1);   // ~XCD id (round-robin dispatch)

    long chunk = (E + BIN_BLOCKS - 1) / BIN_BLOCKS;
    long e0 = (long)blockIdx.x * chunk;
    long e1 = e0 + chunk; if (e1 > E) e1 = E;

    for (int i = tid; i < NBKA; i += 1024) h[i] = 0;
    __syncthreads();

    for (long s0 = e0; s0 < e1; s0 += SUBCHUNK) {
        long s1 = s0 + SUBCHUNK; if (s1 > e1) s1 = e1;
        for (long e = s0 + tid; e < s1; e += 1024) atomicAdd(&h[dst[e] >> 6], 1);
        __syncthreads();
        for (int b = tid; b < NBKA; b += 1024) {
            int c = h[b];
            if (c) { gb[b] = atomicAdd(&cursor[sh * NBKA + b], c); h[b] = 0; }
        }
        __syncthreads();
        for (long e = s0 + tid; e < s1; e += 1024) {
            int d = dst[e];
            int b = d >> 6;
            int lp = atomicAdd(&h[b], 1);
            int pos = gb[b] + lp;
            if (pos < SCAP) bdata[((long)sh * NBKA + b) * SCAP + pos] = ((d & 63) << 17) | src[e];
        }
        __syncthreads();
        for (int b = tid; b < NBKA; b += 1024) h[b] = 0;
        __syncthreads();
    }
}

// one block per bucket: hist over dl -> wave scan -> placement into global
// seds (sorted by dl), run offsets to rsg.
__global__ __launch_bounds__(256) void sort_kernel(
    const int* __restrict__ cursor, const int* __restrict__ bdata,
    int* __restrict__ seds, int* __restrict__ rsg) {
    __shared__ int hist[NPB];
    __shared__ int rs[NPB + 1];
    __shared__ int cur[NPB];
    int tid = threadIdx.x, lane = tid & 63, wid = tid >> 6;
    if (tid < NPB) hist[tid] = 0;
    __syncthreads();

    int b = blockIdx.x;
    int cn[NSHARD];
#pragma unroll
    for (int s = 0; s < NSHARD; ++s) {
        int c = cursor[s * NBKA + b];
        cn[s] = c > SCAP ? SCAP : c;
    }
#pragma unroll
    for (int s = 0; s < NSHARD; ++s) {
        const int* bd = bdata + ((long)s * NBKA + b) * SCAP;
        for (int e = tid; e < cn[s]; e += 256) atomicAdd(&hist[bd[e] >> 17], 1);
    }
    __syncthreads();
    if (wid == 0) {
        int v = hist[lane], s = v;
#pragma unroll
        for (int ofs = 1; ofs < 64; ofs <<= 1) {
            int t = __shfl_up(s, ofs);
            if (lane >= ofs) s += t;
        }
        rs[lane] = s - v;
        cur[lane] = s - v;
        if (lane == 63) rs[64] = s;
    }
    __syncthreads();
    if (tid <= NPB) rsg[b * (NPB + 1) + tid] = rs[tid];
    int* sb = seds + (long)b * BCAP;
#pragma unroll
    for (int s = 0; s < NSHARD; ++s) {
        const int* bd = bdata + ((long)s * NBKA + b) * SCAP;
        for (int e = tid; e < cn[s]; e += 256) {
            int p = bd[e];
            int pos = atomicAdd(&cur[p >> 17], 1);
            if (pos < BCAP) sb[pos] = p & 0x1FFFF;
        }
    }
}

// stage seds run -> wave-per-node register gather of x rows.
__global__ __launch_bounds__(256) void agg1_kernel(const float* __restrict__ x,
                                                   const int* __restrict__ seds,
                                                   const int* __restrict__ rsg,
                                                   float* __restrict__ xsum, int N) {
    __shared__ int eds[BCAP];
    __shared__ int rs[NPB + 1];
    int tid = threadIdx.x, lane = tid & 63, wid = tid >> 6;
    int b = blockIdx.x;
    if (tid <= NPB) {
        int v = rsg[b * (NPB + 1) + tid];
        rs[tid] = v > BCAP ? BCAP : v;
    }
    __syncthreads();
    int cnt = rs[NPB];
    const int* sbp = seds + (long)b * BCAP;
    for (int i = tid; i < cnt; i += 256) eds[i] = sbp[i];
    __syncthreads();

    int slot = lane >> 3, f = lane & 7;
    int base = b * NPB;
    for (int idx = wid; idx < NPB; idx += 4) {
        int n = base + idx;
        if (n >= N) break;
        int start = rs[idx], end = rs[idx + 1];
        float acc = 0.0f, acc2 = 0.0f;
        int e = start + slot;
        for (; e + 8 < end; e += 16) {
            int s0 = eds[e], s1 = eds[e + 8];
            if (f < 7) { acc += x[(long)s0 * 7 + f]; acc2 += x[(long)s1 * 7 + f]; }
        }
        if (e < end) {
            int s0 = eds[e];
            if (f < 7) acc += x[(long)s0 * 7 + f];
        }
        acc += acc2;
        acc += __shfl_xor(acc, 8);
        acc += __shfl_xor(acc, 16);
        acc += __shfl_xor(acc, 32);
        if (slot == 0 && f < 7) xsum[(long)n * 8 + f] = acc + x[(long)n * 7 + f];
    }
}

// h1 = relu(relu(xsum@w1a+b1a)@w2a+b2a); g1h = fp16(h1@w1b). Thread per node.
// Weights direct from global: wave-uniform indices -> scalar s_load path.
__global__ __launch_bounds__(256, 2) void mlpA_kernel(
    const float* __restrict__ xsum,
    const float* __restrict__ w1, const float* __restrict__ b1,
    const float* __restrict__ w2, const float* __restrict__ b2,
    const float* __restrict__ w1b,
    __half* __restrict__ g1h, int N) {
    int n = blockIdx.x * blockDim.x + threadIdx.x;
    if (n >= N) return;

    float xv[7];
#pragma unroll
    for (int j = 0; j < 7; ++j) xv[j] = xsum[(long)n * 8 + j];

    float t[64];
#pragma unroll
    for (int k = 0; k < 64; ++k) {
        float s = b1[k];
#pragma unroll
        for (int j = 0; j < 7; ++j) s = fmaf(xv[j], w1[j * 64 + k], s);
        t[k] = fmaxf(s, 0.0f);
    }

    float g[32];
#pragma unroll
    for (int m = 0; m < 32; ++m) g[m] = 0.0f;
#pragma unroll 2
    for (int k2 = 0; k2 < 64; ++k2) {
        float s = b2[k2];
#pragma unroll
        for (int k = 0; k < 64; ++k) s = fmaf(t[k], w2[k * 64 + k2], s);
        float h = fmaxf(s, 0.0f);
#pragma unroll
        for (int m = 0; m < 32; ++m) g[m] = fmaf(h, w1b[k2 * 32 + m], g[m]);
    }
    __half* gr = g1h + (long)n * 32;
#pragma unroll
    for (int m = 0; m < 32; ++m) gr[m] = __float2half(g[m]);
}

// stage seds run -> wave-per-node __half2 gather of g1h rows (quad=edge,
// f2=feature-pair; 8 rows in flight per lane) + collapsed MLP-B epilogue.
__global__ __launch_bounds__(256) void agg2_kernel(
    const __half* __restrict__ g1h, const int* __restrict__ seds,
    const int* __restrict__ rsg,
    const float* __restrict__ b1b, const float* __restrict__ w2b,
    const float* __restrict__ b2b, const float* __restrict__ wsv,
    float* __restrict__ z1, float* __restrict__ z2, int N) {
    __shared__ int eds[BCAP];
    __shared__ int rs[NPB + 1];
    __shared__ float v1[32], v2[32], sbv[32];
    __shared__ float sc[2];
    int tid = threadIdx.x, lane = tid & 63, wid = tid >> 6;
    int b = blockIdx.x;
    if (tid <= NPB) {
        int v = rsg[b * (NPB + 1) + tid];
        rs[tid] = v > BCAP ? BCAP : v;
    }
    if (tid >= 96 && tid < 128) {
        int m2 = tid - 96;
        float s1 = 0.0f, s2 = 0.0f;
#pragma unroll 8
        for (int m = 0; m < 32; ++m) {
            float w = w2b[m2 * 32 + m];
            s1 = fmaf(w, wsv[m], s1);
            s2 = fmaf(w, wsv[32 + m], s2);
        }
        v1[m2] = s1; v2[m2] = s2; sbv[m2] = b1b[m2];
    }
    if (tid == 128) {
        float c1 = 0.0f, c2 = 0.0f;
        for (int m = 0; m < 32; ++m) { c1 += b2b[m] * wsv[m]; c2 += b2b[m] * wsv[32 + m]; }
        sc[0] = c1; sc[1] = c2;
    }
    __syncthreads();
    int cnt = rs[NPB];
    const int* sbp = seds + (long)b * BCAP;
    for (int i = tid; i < cnt; i += 256) eds[i] = sbp[i];
    __syncthreads();

    int quad = lane >> 4;   // edge slot 0..3
    int f2 = lane & 15;     // half2 feature pair: features 2f2, 2f2+1
    int base = b * NPB;
    for (int idx = wid; idx < NPB; idx += 4) {
        int n = base + idx;
        if (n >= N) break;
        int start = rs[idx], end = rs[idx + 1];
        float2 a0 = {0,0}, a1 = {0,0}, a2 = {0,0}, a3 = {0,0};
        float2 a4 = {0,0}, a5 = {0,0}, a6 = {0,0}, a7 = {0,0};
        int e = start + quad;
        for (; e + 28 < end; e += 32) {
            int s0 = eds[e],      s1 = eds[e + 4],  s2 = eds[e + 8],  s3 = eds[e + 12];
            int s4 = eds[e + 16], s5 = eds[e + 20], s6 = eds[e + 24], s7 = eds[e + 28];
            float2 h0 = __half22float2(reinterpret_cast<const __half2*>(g1h + (long)s0 * 32)[f2]);
            float2 h1 = __half22float2(reinterpret_cast<const __half2*>(g1h + (long)s1 * 32)[f2]);
            float2 h2 = __half22float2(reinterpret_cast<const __half2*>(g1h + (long)s2 * 32)[f2]);
            float2 h3 = __half22float2(reinterpret_cast<const __half2*>(g1h + (long)s3 * 32)[f2]);
            float2 h4 = __half22float2(reinterpret_cast<const __half2*>(g1h + (long)s4 * 32)[f2]);
            float2 h5 = __half22float2(reinterpret_cast<const __half2*>(g1h + (long)s5 * 32)[f2]);
            float2 h6 = __half22float2(reinterpret_cast<const __half2*>(g1h + (long)s6 * 32)[f2]);
            float2 h7 = __half22float2(reinterpret_cast<const __half2*>(g1h + (long)s7 * 32)[f2]);
            a0.x += h0.x; a0.y += h0.y; a1.x += h1.x; a1.y += h1.y;
            a2.x += h2.x; a2.y += h2.y; a3.x += h3.x; a3.y += h3.y;
            a4.x += h4.x; a4.y += h4.y; a5.x += h5.x; a5.y += h5.y;
            a6.x += h6.x; a6.y += h6.y; a7.x += h7.x; a7.y += h7.y;
        }
        for (; e < end; e += 4) {
            float2 h = __half22float2(reinterpret_cast<const __half2*>(g1h + (long)eds[e] * 32)[f2]);
            a0.x += h.x; a0.y += h.y;
        }
        float accx = ((a0.x + a1.x) + (a2.x + a3.x)) + ((a4.x + a5.x) + (a6.x + a7.x));
        float accy = ((a0.y + a1.y) + (a2.y + a3.y)) + ((a4.y + a5.y) + (a6.y + a7.y));
        accx += __shfl_xor(accx, 16); accx += __shfl_xor(accx, 32);
        accy += __shfl_xor(accy, 16); accy += __shfl_xor(accy, 32);
        if (quad == 0) {
            int f0 = 2 * f2, f1 = f0 + 1;
            float2 self = __half22float2(reinterpret_cast<const __half2*>(g1h + (long)n * 32)[f2]);
            float u0 = fmaxf(accx + self.x + sbv[f0], 0.0f);
            float u1 = fmaxf(accy + self.y + sbv[f1], 0.0f);
            float p1 = u0 * v1[f0] + u1 * v1[f1];
            float p2 = u0 * v2[f0] + u1 * v2[f1];
#pragma unroll
            for (int m = 1; m < 16; m <<= 1) {
                p1 += __shfl_xor(p1, m);
                p2 += __shfl_xor(p2, m);
            }
            if (f2 == 0) { z1[n] = p1 + sc[0]; z2[n] = p2 + sc[1]; }
        }
    }
}

__global__ void score_kernel(const int* __restrict__ cand,
                             const float* __restrict__ z1,
                             const float* __restrict__ z2,
                             const float* __restrict__ bs,
                             float* __restrict__ out, int C) {
    int c = blockIdx.x * blockDim.x + threadIdx.x;
    if (c >= C) return;
    int a = cand[2 * c], b = cand[2 * c + 1];
    float s = z1[a] + z2[b] + bs[0];
    out[c] = 1.0f / (1.0f + expf(-s));
}

extern "C" void kernel_launch(void* const* d_in, const int* in_sizes, int n_in,
                              void* d_out, int out_size, void* d_ws, size_t ws_size,
                              hipStream_t stream) {
    const float* x   = (const float*)d_in[0];
    const int* edge  = (const int*)d_in[1];
    const int* cand  = (const int*)d_in[2];
    const float* w1a = (const float*)d_in[3];
    const float* b1a = (const float*)d_in[4];
    const float* w2a = (const float*)d_in[5];
    const float* b2a = (const float*)d_in[6];
    const float* w1b = (const float*)d_in[7];
    const float* b1b = (const float*)d_in[8];
    const float* w2b = (const float*)d_in[9];
    const float* b2b = (const float*)d_in[10];
    const float* wsv = (const float*)d_in[11];
    const float* bs  = (const float*)d_in[12];

    const int  N = in_sizes[0] / 7;
    const long E = in_sizes[1] / 2;
    const int  C = in_sizes[2] / 2;
    const int* src = edge;
    const int* dst = edge + E;
    const int NB = (N + NPB - 1) / NPB;

    // ws: cursor 8*1600 | bdata 8*1600*SCAP (32.8MB) | seds NB*BCAP (28.8MB)
    //   | rsg NB*65 | xsum N*8 | g1h N*32 half | z1,z2   => ~73 MB
    int* cursor = (int*)d_ws;
    int* bdata  = cursor + NSHARD * NBKA;
    int* seds   = bdata + (size_t)NSHARD * NBKA * SCAP;
    int* rsg    = seds + (size_t)NB * BCAP;
    float* xsum = (float*)(rsg + (size_t)NB * (NPB + 1));
    __half* g1h = (__half*)(xsum + (size_t)N * 8);
    float* z1   = (float*)(g1h + (size_t)N * 32);
    float* z2   = z1 + N;
    (void)ws_size;

    hipMemsetAsync(cursor, 0, (size_t)NSHARD * NBKA * sizeof(int), stream);

    bin_kernel<<<BIN_BLOCKS, 1024, 0, stream>>>(src, dst, cursor, bdata, E);
    sort_kernel<<<NB, 256, 0, stream>>>(cursor, bdata, seds, rsg);
    agg1_kernel<<<NB, 256, 0, stream>>>(x, seds, rsg, xsum, N);
    {
        int blocks = (N + 255) / 256;
        mlpA_kernel<<<blocks, 256, 0, stream>>>(xsum, w1a, b1a, w2a, b2a, w1b, g1h, N);
    }
    agg2_kernel<<<NB, 256, 0, stream>>>(g1h, seds, rsg, b1b, w2b, b2b, wsv, z1, z2, N);
    {
        int blocks = (C + 255) / 256;
        score_kernel<<<blocks, 256, 0, stream>>>(cand, z1, z2, bs, (float*)d_out, C);
    }
}

// Round 13
// 357.802 us; speedup vs baseline: 1.0649x; 1.0649x over previous
//
#include <hip/hip_runtime.h>
#include <hip/hip_fp16.h>
#include <math.h>

// ---------------------------------------------------------------------------
// GIN link scorer. Pipeline:
//   bin:  XCD-sharded, sub-chunk-reserved binning of edges into 1563 buckets
//         of 64 dst nodes (payload (dstlow<<17)|src).
//   sort_agg1: per bucket: hist -> wave scan -> LDS placement (the dst-sort),
//         coalesced dump to global seds+rsg (for agg2), then wave-per-node
//         gather x[src] -> xsum. (R12: standalone sort did scattered global
//         writes + bdata/seds re-reads; fusing removed ~30us.)
//   mlpA: weights direct from global (wave-uniform -> s_load scalar path,
//         R10), launch_bounds(256,2) so t[64] stays in VGPRs (R7).
//         h1 = relu(relu(xsum@w1a+b1a)@w2a+b2a); g1h = fp16(h1@w1b) [N,32].
//   agg2: stage seds run -> wave-per-node gather g1h rows via __half2
//         (quad=edge slot, f2=feature pair; 8 rows in flight/lane);
//         u = relu(hsum+self+b1b); z1=u.v1+c1, z2=u.v2+c2 (MLP-B collapsed).
//   score: out[c] = sigmoid(z1[a]+z2[b]+bs).
// ---------------------------------------------------------------------------

#define NPB 64        // nodes per bucket
#define NBKA 1600     // allocated buckets (1563 used)
#define NSHARD 8
#define SCAP 640      // per shard-bucket capacity; mean 500, sigma 22 -> +6σ
#define BCAP 4608     // per-bucket capacity; mean 4096, sigma 64 -> +8σ
#define BIN_BLOCKS 256
#define SUBCHUNK 8192

__global__ __launch_bounds__(1024) void bin_kernel(
    const int* __restrict__ src, const int* __restrict__ dst,
    int* __restrict__ cursor, int* __restrict__ bdata, long E) {
    __shared__ int h[NBKA];    // per-sub-chunk counts, then local cursor
    __shared__ int gb[NBKA];   // reserved global base per bucket
    int tid = threadIdx.x;
    int sh = blockIdx.x & (NSHARD - 1);   // ~XCD id (round-robin dispatch)

    long chunk = (E + BIN_BLOCKS - 1) / BIN_BLOCKS;
    long e0 = (long)blockIdx.x * chunk;
    long e1 = e0 + chunk; if (e1 > E) e1 = E;

    for (int i = tid; i < NBKA; i += 1024) h[i] = 0;
    __syncthreads();

    for (long s0 = e0; s0 < e1; s0 += SUBCHUNK) {
        long s1 = s0 + SUBCHUNK; if (s1 > e1) s1 = e1;
        for (long e = s0 + tid; e < s1; e += 1024) atomicAdd(&h[dst[e] >> 6], 1);
        __syncthreads();
        for (int b = tid; b < NBKA; b += 1024) {
            int c = h[b];
            if (c) { gb[b] = atomicAdd(&cursor[sh * NBKA + b], c); h[b] = 0; }
        }
        __syncthreads();
        for (long e = s0 + tid; e < s1; e += 1024) {
            int d = dst[e];
            int b = d >> 6;
            int lp = atomicAdd(&h[b], 1);
            int pos = gb[b] + lp;
            if (pos < SCAP) bdata[((long)sh * NBKA + b) * SCAP + pos] = ((d & 63) << 17) | src[e];
        }
        __syncthreads();
        for (int b = tid; b < NBKA; b += 1024) h[b] = 0;
        __syncthreads();
    }
}

// fused: build dst-sorted edge list in LDS, dump coalesced to seds/rsg,
// then wave-per-node gather of x rows -> xsum.
__global__ __launch_bounds__(256) void sort_agg1_kernel(
    const float* __restrict__ x,
    const int* __restrict__ cursor, const int* __restrict__ bdata,
    int* __restrict__ seds, int* __restrict__ rsg,
    float* __restrict__ xsum, int N) {
    __shared__ int eds[BCAP];
    __shared__ int hist[NPB];
    __shared__ int rs[NPB + 1];
    __shared__ int cur[NPB];
    int tid = threadIdx.x, lane = tid & 63, wid = tid >> 6;
    if (tid < NPB) hist[tid] = 0;
    __syncthreads();

    int b = blockIdx.x;
    int cn[NSHARD];
#pragma unroll
    for (int s = 0; s < NSHARD; ++s) {
        int c = cursor[s * NBKA + b];
        cn[s] = c > SCAP ? SCAP : c;
    }

#pragma unroll
    for (int s = 0; s < NSHARD; ++s) {
        const int* bd = bdata + ((long)s * NBKA + b) * SCAP;
        for (int e = tid; e < cn[s]; e += 256) atomicAdd(&hist[bd[e] >> 17], 1);
    }
    __syncthreads();
    if (wid == 0) {
        int v = hist[lane], s = v;
#pragma unroll
        for (int ofs = 1; ofs < 64; ofs <<= 1) {
            int t = __shfl_up(s, ofs);
            if (lane >= ofs) s += t;
        }
        rs[lane] = s - v;
        cur[lane] = s - v;
        if (lane == 63) rs[64] = s;
    }
    __syncthreads();
#pragma unroll
    for (int s = 0; s < NSHARD; ++s) {
        const int* bd = bdata + ((long)s * NBKA + b) * SCAP;
        for (int e = tid; e < cn[s]; e += 256) {
            int p = bd[e];
            int pos = atomicAdd(&cur[p >> 17], 1);
            if (pos < BCAP) eds[pos] = p & 0x1FFFF;
        }
    }
    __syncthreads();

    // coalesced dump for agg2
    if (tid <= NPB) rsg[b * (NPB + 1) + tid] = rs[tid];
    int cnt = rs[NPB];
    int* sb = seds + (long)b * BCAP;
    for (int i = tid; i < cnt; i += 256) sb[i] = eds[i];

    // layer-1 gather
    int slot = lane >> 3, f = lane & 7;
    int base = b * NPB;
    for (int idx = wid; idx < NPB; idx += 4) {
        int n = base + idx;
        if (n >= N) break;
        int start = rs[idx], end = rs[idx + 1];
        float acc = 0.0f, acc2 = 0.0f;
        int e = start + slot;
        for (; e + 8 < end; e += 16) {
            int s0 = eds[e], s1 = eds[e + 8];
            if (f < 7) { acc += x[(long)s0 * 7 + f]; acc2 += x[(long)s1 * 7 + f]; }
        }
        if (e < end) {
            int s0 = eds[e];
            if (f < 7) acc += x[(long)s0 * 7 + f];
        }
        acc += acc2;
        acc += __shfl_xor(acc, 8);
        acc += __shfl_xor(acc, 16);
        acc += __shfl_xor(acc, 32);
        if (slot == 0 && f < 7) xsum[(long)n * 8 + f] = acc + x[(long)n * 7 + f];
    }
}

// h1 = relu(relu(xsum@w1a+b1a)@w2a+b2a); g1h = fp16(h1@w1b). Thread per node.
// Weights direct from global: wave-uniform indices -> scalar s_load path.
__global__ __launch_bounds__(256, 2) void mlpA_kernel(
    const float* __restrict__ xsum,
    const float* __restrict__ w1, const float* __restrict__ b1,
    const float* __restrict__ w2, const float* __restrict__ b2,
    const float* __restrict__ w1b,
    __half* __restrict__ g1h, int N) {
    int n = blockIdx.x * blockDim.x + threadIdx.x;
    if (n >= N) return;

    float xv[7];
#pragma unroll
    for (int j = 0; j < 7; ++j) xv[j] = xsum[(long)n * 8 + j];

    float t[64];
#pragma unroll
    for (int k = 0; k < 64; ++k) {
        float s = b1[k];
#pragma unroll
        for (int j = 0; j < 7; ++j) s = fmaf(xv[j], w1[j * 64 + k], s);
        t[k] = fmaxf(s, 0.0f);
    }

    float g[32];
#pragma unroll
    for (int m = 0; m < 32; ++m) g[m] = 0.0f;
#pragma unroll 2
    for (int k2 = 0; k2 < 64; ++k2) {
        float s = b2[k2];
#pragma unroll
        for (int k = 0; k < 64; ++k) s = fmaf(t[k], w2[k * 64 + k2], s);
        float h = fmaxf(s, 0.0f);
#pragma unroll
        for (int m = 0; m < 32; ++m) g[m] = fmaf(h, w1b[k2 * 32 + m], g[m]);
    }
    __half* gr = g1h + (long)n * 32;
#pragma unroll
    for (int m = 0; m < 32; ++m) gr[m] = __float2half(g[m]);
}

// stage seds run -> wave-per-node __half2 gather of g1h rows (quad=edge,
// f2=feature-pair; 8 rows in flight per lane) + collapsed MLP-B epilogue.
__global__ __launch_bounds__(256) void agg2_kernel(
    const __half* __restrict__ g1h, const int* __restrict__ seds,
    const int* __restrict__ rsg,
    const float* __restrict__ b1b, const float* __restrict__ w2b,
    const float* __restrict__ b2b, const float* __restrict__ wsv,
    float* __restrict__ z1, float* __restrict__ z2, int N) {
    __shared__ int eds[BCAP];
    __shared__ int rs[NPB + 1];
    __shared__ float v1[32], v2[32], sbv[32];
    __shared__ float sc[2];
    int tid = threadIdx.x, lane = tid & 63, wid = tid >> 6;
    int b = blockIdx.x;
    if (tid <= NPB) {
        int v = rsg[b * (NPB + 1) + tid];
        rs[tid] = v > BCAP ? BCAP : v;
    }
    if (tid >= 96 && tid < 128) {
        int m2 = tid - 96;
        float s1 = 0.0f, s2 = 0.0f;
#pragma unroll 8
        for (int m = 0; m < 32; ++m) {
            float w = w2b[m2 * 32 + m];
            s1 = fmaf(w, wsv[m], s1);
            s2 = fmaf(w, wsv[32 + m], s2);
        }
        v1[m2] = s1; v2[m2] = s2; sbv[m2] = b1b[m2];
    }
    if (tid == 128) {
        float c1 = 0.0f, c2 = 0.0f;
        for (int m = 0; m < 32; ++m) { c1 += b2b[m] * wsv[m]; c2 += b2b[m] * wsv[32 + m]; }
        sc[0] = c1; sc[1] = c2;
    }
    __syncthreads();
    int cnt = rs[NPB];
    const int* sbp = seds + (long)b * BCAP;
    for (int i = tid; i < cnt; i += 256) eds[i] = sbp[i];
    __syncthreads();

    int quad = lane >> 4;   // edge slot 0..3
    int f2 = lane & 15;     // half2 feature pair: features 2f2, 2f2+1
    int base = b * NPB;
    for (int idx = wid; idx < NPB; idx += 4) {
        int n = base + idx;
        if (n >= N) break;
        int start = rs[idx], end = rs[idx + 1];
        float2 a0 = {0,0}, a1 = {0,0}, a2 = {0,0}, a3 = {0,0};
        float2 a4 = {0,0}, a5 = {0,0}, a6 = {0,0}, a7 = {0,0};
        int e = start + quad;
        for (; e + 28 < end; e += 32) {
            int s0 = eds[e],      s1 = eds[e + 4],  s2 = eds[e + 8],  s3 = eds[e + 12];
            int s4 = eds[e + 16], s5 = eds[e + 20], s6 = eds[e + 24], s7 = eds[e + 28];
            float2 h0 = __half22float2(reinterpret_cast<const __half2*>(g1h + (long)s0 * 32)[f2]);
            float2 h1 = __half22float2(reinterpret_cast<const __half2*>(g1h + (long)s1 * 32)[f2]);
            float2 h2 = __half22float2(reinterpret_cast<const __half2*>(g1h + (long)s2 * 32)[f2]);
            float2 h3 = __half22float2(reinterpret_cast<const __half2*>(g1h + (long)s3 * 32)[f2]);
            float2 h4 = __half22float2(reinterpret_cast<const __half2*>(g1h + (long)s4 * 32)[f2]);
            float2 h5 = __half22float2(reinterpret_cast<const __half2*>(g1h + (long)s5 * 32)[f2]);
            float2 h6 = __half22float2(reinterpret_cast<const __half2*>(g1h + (long)s6 * 32)[f2]);
            float2 h7 = __half22float2(reinterpret_cast<const __half2*>(g1h + (long)s7 * 32)[f2]);
            a0.x += h0.x; a0.y += h0.y; a1.x += h1.x; a1.y += h1.y;
            a2.x += h2.x; a2.y += h2.y; a3.x += h3.x; a3.y += h3.y;
            a4.x += h4.x; a4.y += h4.y; a5.x += h5.x; a5.y += h5.y;
            a6.x += h6.x; a6.y += h6.y; a7.x += h7.x; a7.y += h7.y;
        }
        for (; e < end; e += 4) {
            float2 h = __half22float2(reinterpret_cast<const __half2*>(g1h + (long)eds[e] * 32)[f2]);
            a0.x += h.x; a0.y += h.y;
        }
        float accx = ((a0.x + a1.x) + (a2.x + a3.x)) + ((a4.x + a5.x) + (a6.x + a7.x));
        float accy = ((a0.y + a1.y) + (a2.y + a3.y)) + ((a4.y + a5.y) + (a6.y + a7.y));
        accx += __shfl_xor(accx, 16); accx += __shfl_xor(accx, 32);
        accy += __shfl_xor(accy, 16); accy += __shfl_xor(accy, 32);
        if (quad == 0) {
            int f0 = 2 * f2, f1 = f0 + 1;
            float2 self = __half22float2(reinterpret_cast<const __half2*>(g1h + (long)n * 32)[f2]);
            float u0 = fmaxf(accx + self.x + sbv[f0], 0.0f);
            float u1 = fmaxf(accy + self.y + sbv[f1], 0.0f);
            float p1 = u0 * v1[f0] + u1 * v1[f1];
            float p2 = u0 * v2[f0] + u1 * v2[f1];
#pragma unroll
            for (int m = 1; m < 16; m <<= 1) {
                p1 += __shfl_xor(p1, m);
                p2 += __shfl_xor(p2, m);
            }
            if (f2 == 0) { z1[n] = p1 + sc[0]; z2[n] = p2 + sc[1]; }
        }
    }
}

__global__ void score_kernel(const int* __restrict__ cand,
                             const float* __restrict__ z1,
                             const float* __restrict__ z2,
                             const float* __restrict__ bs,
                             float* __restrict__ out, int C) {
    int c = blockIdx.x * blockDim.x + threadIdx.x;
    if (c >= C) return;
    int a = cand[2 * c], b = cand[2 * c + 1];
    float s = z1[a] + z2[b] + bs[0];
    out[c] = 1.0f / (1.0f + expf(-s));
}

extern "C" void kernel_launch(void* const* d_in, const int* in_sizes, int n_in,
                              void* d_out, int out_size, void* d_ws, size_t ws_size,
                              hipStream_t stream) {
    const float* x   = (const float*)d_in[0];
    const int* edge  = (const int*)d_in[1];
    const int* cand  = (const int*)d_in[2];
    const float* w1a = (const float*)d_in[3];
    const float* b1a = (const float*)d_in[4];
    const float* w2a = (const float*)d_in[5];
    const float* b2a = (const float*)d_in[6];
    const float* w1b = (const float*)d_in[7];
    const float* b1b = (const float*)d_in[8];
    const float* w2b = (const float*)d_in[9];
    const float* b2b = (const float*)d_in[10];
    const float* wsv = (const float*)d_in[11];
    const float* bs  = (const float*)d_in[12];

    const int  N = in_sizes[0] / 7;
    const long E = in_sizes[1] / 2;
    const int  C = in_sizes[2] / 2;
    const int* src = edge;
    const int* dst = edge + E;
    const int NB = (N + NPB - 1) / NPB;

    // ws: cursor 8*1600 | bdata 8*1600*SCAP (32.8MB) | seds NB*BCAP (28.8MB)
    //   | rsg NB*65 | xsum N*8 | g1h N*32 half | z1,z2   => ~73 MB
    int* cursor = (int*)d_ws;
    int* bdata  = cursor + NSHARD * NBKA;
    int* seds   = bdata + (size_t)NSHARD * NBKA * SCAP;
    int* rsg    = seds + (size_t)NB * BCAP;
    float* xsum = (float*)(rsg + (size_t)NB * (NPB + 1));
    __half* g1h = (__half*)(xsum + (size_t)N * 8);
    float* z1   = (float*)(g1h + (size_t)N * 32);
    float* z2   = z1 + N;
    (void)ws_size;

    hipMemsetAsync(cursor, 0, (size_t)NSHARD * NBKA * sizeof(int), stream);

    bin_kernel<<<BIN_BLOCKS, 1024, 0, stream>>>(src, dst, cursor, bdata, E);
    sort_agg1_kernel<<<NB, 256, 0, stream>>>(x, cursor, bdata, seds, rsg, xsum, N);
    {
        int blocks = (N + 255) / 256;
        mlpA_kernel<<<blocks, 256, 0, stream>>>(xsum, w1a, b1a, w2a, b2a, w1b, g1h, N);
    }
    agg2_kernel<<<NB, 256, 0, stream>>>(g1h, seds, rsg, b1b, w2b, b2b, wsv, z1, z2, N);
    {
        int blocks = (C + 255) / 256;
        score_kernel<<<blocks, 256, 0, stream>>>(cand, z1, z2, bs, (float*)d_out, C);
    }
}